// Round 1
// baseline (376.170 us; speedup 1.0000x reference)
//
#include <hip/hip_runtime.h>
#include <hip/hip_bf16.h>
#include <math.h>

#define B_ 4
#define T_ 4096
#define C_ 384
#define H_ 64

typedef __attribute__((ext_vector_type(8))) short bf16x8;
typedef __attribute__((ext_vector_type(4))) float f32x4;

// ---------------- Projection: q,k,v = x @ {Wq,Wk,Wv}, fp32 accum, bf16 out ----
// grid: B*T/4 blocks of 256 threads; wave w handles row row0+w, lane = out col.
__global__ __launch_bounds__(256) void proj_kernel(
    const float* __restrict__ x, const float* __restrict__ Wk,
    const float* __restrict__ Wq, const float* __restrict__ Wv,
    __hip_bfloat16* __restrict__ qb, __hip_bfloat16* __restrict__ kb,
    __hip_bfloat16* __restrict__ vb)
{
  __shared__ float xs[4 * C_];
  const int row0 = blockIdx.x * 4;
  const int tid = threadIdx.x;
  const float* xrow = x + (size_t)row0 * C_;
  for (int i = tid; i < 4 * C_; i += 256) xs[i] = xrow[i];
  __syncthreads();

  const int w = tid >> 6;    // wave id == local row
  const int lane = tid & 63; // output column (H_ == 64)
  const float* xr = xs + w * C_;
  float ak = 0.f, aq = 0.f, av = 0.f;
  #pragma unroll 4
  for (int c = 0; c < C_; ++c) {
    const float xc = xr[c];
    ak = fmaf(xc, Wk[c * H_ + lane], ak);
    aq = fmaf(xc, Wq[c * H_ + lane], aq);
    av = fmaf(xc, Wv[c * H_ + lane], av);
  }
  const size_t o = (size_t)(row0 + w) * H_ + lane;
  qb[o] = __float2bfloat16(aq);
  kb[o] = __float2bfloat16(ak);
  vb[o] = __float2bfloat16(av);
}

// ---------------- Flash attention, causal, 1 wave per 16 q-rows --------------
// S = Q K^T * 384^-0.5 ; causal mask ; online softmax ; O = P V ; out fp32.
// MFMA 16x16x32 bf16 layouts:
//   A/B frag: row|col = lane&15, k = (lane>>4)*8 + j   (8 contiguous bf16)
//   C/D frag: col = lane&15, row = (lane>>4)*4 + r     (4 f32)
__global__ __launch_bounds__(64) void attn_kernel(
    const __hip_bfloat16* __restrict__ qb, const __hip_bfloat16* __restrict__ kb,
    const __hip_bfloat16* __restrict__ vb, float* __restrict__ out)
{
  __shared__ __hip_bfloat16 plds[16 * 32];

  const int qi = (T_ / 16 - 1) - blockIdx.x;  // reversed: longest blocks first
  const int b  = blockIdx.y;
  const int q0 = qi * 16;
  const int lane = threadIdx.x;
  const int lrow = lane & 15;
  const int lgrp = lane >> 4;

  const __hip_bfloat16* Q = qb + (size_t)b * T_ * H_;
  const __hip_bfloat16* K = kb + (size_t)b * T_ * H_;
  const __hip_bfloat16* V = vb + (size_t)b * T_ * H_;

  // Q A-fragments (held in registers for whole kernel)
  const bf16x8 qf0 = *(const bf16x8*)(Q + (size_t)(q0 + lrow) * H_ + lgrp * 8);
  const bf16x8 qf1 = *(const bf16x8*)(Q + (size_t)(q0 + lrow) * H_ + 32 + lgrp * 8);

  f32x4 o0{0,0,0,0}, o1{0,0,0,0}, o2{0,0,0,0}, o3{0,0,0,0};
  float m[4], l[4];
  #pragma unroll
  for (int r = 0; r < 4; ++r) { m[r] = -INFINITY; l[r] = 0.f; }

  const float sc = 0.05103103630798288f;  // 384^-0.5 (reference scales by C^-0.5)

  const int ntiles = qi + 1;            // 16-wide kv tiles needed (causal)
  const int nch = (ntiles + 1) >> 1;    // 32-wide chunks (last may be half-masked)

  for (int ch = 0; ch < nch; ++ch) {
    const int kv0 = ch * 32;

    // ---- S = Q K^T for two 16-col tiles ----
    f32x4 s0{0,0,0,0}, s1{0,0,0,0};
    {
      const __hip_bfloat16* Kp = K + (size_t)(kv0 + lrow) * H_ + lgrp * 8;
      bf16x8 k0 = *(const bf16x8*)(Kp);
      bf16x8 k1 = *(const bf16x8*)(Kp + 32);
      s0 = __builtin_amdgcn_mfma_f32_16x16x32_bf16(qf0, k0, s0, 0, 0, 0);
      s0 = __builtin_amdgcn_mfma_f32_16x16x32_bf16(qf1, k1, s0, 0, 0, 0);
      const __hip_bfloat16* Kp2 = K + (size_t)(kv0 + 16 + lrow) * H_ + lgrp * 8;
      bf16x8 k2 = *(const bf16x8*)(Kp2);
      bf16x8 k3 = *(const bf16x8*)(Kp2 + 32);
      s1 = __builtin_amdgcn_mfma_f32_16x16x32_bf16(qf0, k2, s1, 0, 0, 0);
      s1 = __builtin_amdgcn_mfma_f32_16x16x32_bf16(qf1, k3, s1, 0, 0, 0);
    }

    // ---- scale + causal mask ----
    #pragma unroll
    for (int r = 0; r < 4; ++r) {
      const int rg = q0 + lgrp * 4 + r;
      float v0 = s0[r] * sc, v1 = s1[r] * sc;
      if (kv0 + lrow > rg)      v0 = -INFINITY;
      if (kv0 + 16 + lrow > rg) v1 = -INFINITY;
      s0[r] = v0; s1[r] = v1;
    }

    // ---- online softmax ----
    float cm[4], cs[4], alpha[4];
    #pragma unroll
    for (int r = 0; r < 4; ++r) cm[r] = fmaxf(s0[r], s1[r]);
    #pragma unroll
    for (int d = 1; d < 16; d <<= 1) {
      #pragma unroll
      for (int r = 0; r < 4; ++r) cm[r] = fmaxf(cm[r], __shfl_xor(cm[r], d, 64));
    }
    #pragma unroll
    for (int r = 0; r < 4; ++r) {
      const float nm = fmaxf(m[r], cm[r]);
      alpha[r] = __expf(m[r] - nm);       // 0 on first chunk (m=-inf)
      m[r] = nm;
      s0[r] = __expf(s0[r] - nm);         // masked -> exp(-inf)=0
      s1[r] = __expf(s1[r] - nm);
      cs[r] = s0[r] + s1[r];
    }
    #pragma unroll
    for (int d = 1; d < 16; d <<= 1) {
      #pragma unroll
      for (int r = 0; r < 4; ++r) cs[r] += __shfl_xor(cs[r], d, 64);
    }
    #pragma unroll
    for (int r = 0; r < 4; ++r) {
      l[r] = l[r] * alpha[r] + cs[r];
      o0[r] *= alpha[r]; o1[r] *= alpha[r]; o2[r] *= alpha[r]; o3[r] *= alpha[r];
    }

    // ---- P (C-layout) -> LDS -> A-layout fragment ----
    __syncthreads();
    #pragma unroll
    for (int r = 0; r < 4; ++r) {
      const int row = lgrp * 4 + r;
      plds[row * 32 + lrow]      = __float2bfloat16(s0[r]);
      plds[row * 32 + 16 + lrow] = __float2bfloat16(s1[r]);
    }
    __syncthreads();
    const bf16x8 pf = *(const bf16x8*)(plds + lrow * 32 + lgrp * 8);

    // ---- O += P V  (V B-frag: col=h=n*16+lrow, k=kv=lgrp*8+j) ----
    const short* Vs = (const short*)V;
    #pragma unroll
    for (int n = 0; n < 4; ++n) {
      bf16x8 vf;
      #pragma unroll
      for (int j = 0; j < 8; ++j)
        ((short*)&vf)[j] = Vs[(size_t)(kv0 + lgrp * 8 + j) * H_ + n * 16 + lrow];
      if (n == 0) o0 = __builtin_amdgcn_mfma_f32_16x16x32_bf16(pf, vf, o0, 0, 0, 0);
      if (n == 1) o1 = __builtin_amdgcn_mfma_f32_16x16x32_bf16(pf, vf, o1, 0, 0, 0);
      if (n == 2) o2 = __builtin_amdgcn_mfma_f32_16x16x32_bf16(pf, vf, o2, 0, 0, 0);
      if (n == 3) o3 = __builtin_amdgcn_mfma_f32_16x16x32_bf16(pf, vf, o3, 0, 0, 0);
    }
  }

  // ---- epilogue: divide by l, write fp32 ----
  float* op = out + ((size_t)b * T_ + q0) * H_;
  #pragma unroll
  for (int r = 0; r < 4; ++r) {
    const float inv = 1.0f / l[r];
    const int row = lgrp * 4 + r;
    op[row * H_ +  0 + lrow] = o0[r] * inv;
    op[row * H_ + 16 + lrow] = o1[r] * inv;
    op[row * H_ + 32 + lrow] = o2[r] * inv;
    op[row * H_ + 48 + lrow] = o3[r] * inv;
  }
}

extern "C" void kernel_launch(void* const* d_in, const int* in_sizes, int n_in,
                              void* d_out, int out_size, void* d_ws, size_t ws_size,
                              hipStream_t stream) {
  const float* x  = (const float*)d_in[0];
  const float* Wk = (const float*)d_in[1];
  const float* Wq = (const float*)d_in[2];
  const float* Wv = (const float*)d_in[3];
  float* out = (float*)d_out;

  const size_t ntok = (size_t)B_ * T_;          // 16384
  __hip_bfloat16* qb = (__hip_bfloat16*)d_ws;
  __hip_bfloat16* kb = qb + ntok * H_;
  __hip_bfloat16* vb = kb + ntok * H_;

  proj_kernel<<<(int)(ntok / 4), 256, 0, stream>>>(x, Wk, Wq, Wv, qb, kb, vb);
  attn_kernel<<<dim3(T_ / 16, B_), 64, 0, stream>>>(qb, kb, vb, out);
}

// Round 2
// 233.870 us; speedup vs baseline: 1.6085x; 1.6085x over previous
//
#include <hip/hip_runtime.h>
#include <hip/hip_bf16.h>
#include <math.h>

#define B_ 4
#define T_ 4096
#define C_ 384
#define H_ 64

typedef __attribute__((ext_vector_type(8))) short bf16x8;
typedef __attribute__((ext_vector_type(4))) float f32x4;

static __device__ __forceinline__ short f2bf(float f) {
  return (short)(((__hip_bfloat16_raw)__float2bfloat16(f)).x);
}

// ---------------- W convert+transpose: Wt[w][h][c] bf16, w in {k,q,v} --------
__global__ __launch_bounds__(256) void wconv_kernel(
    const float* __restrict__ Wk, const float* __restrict__ Wq,
    const float* __restrict__ Wv, short* __restrict__ Wt)
{
  const int w3 = blockIdx.x;
  const float* W = (w3 == 0) ? Wk : (w3 == 1) ? Wq : Wv;
  short* o = Wt + w3 * (H_ * C_);
  for (int i = threadIdx.x; i < H_ * C_; i += 256) {
    const int h = i / C_, c = i - h * C_;
    o[i] = f2bf(W[c * H_ + h]);   // contiguous writes, strided reads (L2)
  }
}

// ---------------- Projection via MFMA: q,k,v = x @ W, bf16 out ---------------
// Block: 256 thr / 4 waves, 64 x-rows. LDS holds x tile as swizzled bf16.
__global__ __launch_bounds__(256) void proj_mfma(
    const float* __restrict__ x, const short* __restrict__ Wt,
    __hip_bfloat16* __restrict__ qb, __hip_bfloat16* __restrict__ kb,
    __hip_bfloat16* __restrict__ vb)
{
  __shared__ __align__(16) char xs[64 * 768];   // [64 rows][384 bf16] swizzled
  const int tid = threadIdx.x;
  const int qblk = blockIdx.x * 64;

  // stage x tile: 3072 16B units; unit u -> row=u/48, col16=u%48
  #pragma unroll
  for (int i = 0; i < 12; ++i) {
    const int u = i * 256 + tid;
    const int row = u / 48, cc = u - row * 48;
    const float* gp = x + (size_t)(qblk + row) * C_ + cc * 8;
    const float4 f0 = *(const float4*)gp;
    const float4 f1 = *(const float4*)(gp + 4);
    bf16x8 bv;
    bv[0] = f2bf(f0.x); bv[1] = f2bf(f0.y); bv[2] = f2bf(f0.z); bv[3] = f2bf(f0.w);
    bv[4] = f2bf(f1.x); bv[5] = f2bf(f1.y); bv[6] = f2bf(f1.z); bv[7] = f2bf(f1.w);
    *(bf16x8*)(xs + ((row * 768 + cc * 16) ^ ((row & 7) << 4))) = bv;
  }
  __syncthreads();

  const int wave = tid >> 6;
  const int lane = tid & 63;
  const int lrow = lane & 15;
  const int lgrp = lane >> 4;
  const int swzA = (lrow & 7) << 4;

  // A-fragments for this wave's 16 rows, all 12 k-steps
  bf16x8 af[12];
  const int rb = (wave * 16 + lrow) * 768;
  #pragma unroll
  for (int ks = 0; ks < 12; ++ks)
    af[ks] = *(const bf16x8*)(xs + ((rb + ks * 64 + lgrp * 16) ^ swzA));

  #pragma unroll
  for (int w3 = 0; w3 < 3; ++w3) {
    __hip_bfloat16* outp = (w3 == 0) ? kb : (w3 == 1) ? qb : vb;
    const short* Wp = Wt + w3 * (H_ * C_);
    #pragma unroll
    for (int n = 0; n < 4; ++n) {
      f32x4 acc = {0.f, 0.f, 0.f, 0.f};
      const short* wb = Wp + (n * 16 + lrow) * C_;
      #pragma unroll
      for (int ks = 0; ks < 12; ++ks) {
        const bf16x8 bf = *(const bf16x8*)(wb + ks * 32 + lgrp * 8);
        acc = __builtin_amdgcn_mfma_f32_16x16x32_bf16(af[ks], bf, acc, 0, 0, 0);
      }
      #pragma unroll
      for (int r = 0; r < 4; ++r) {
        const int row = qblk + wave * 16 + lgrp * 4 + r;
        outp[(size_t)row * H_ + n * 16 + lrow] = __float2bfloat16(acc[r]);
      }
    }
  }
}

// ---------------- Flash attention: 2 waves/block, 32 q-rows, KV chunks of 64 -
// K LDS [kv][64] bf16 swizzled; V LDS transposed [h][kv] bf16 swizzled;
// P per-wave [16][64] bf16 swizzled. All frag reads = ds_read_b128.
#define KVB 64
#define BQ 32

__global__ __launch_bounds__(128) void attn_kernel(
    const __hip_bfloat16* __restrict__ qb, const __hip_bfloat16* __restrict__ kb,
    const __hip_bfloat16* __restrict__ vb, float* __restrict__ out)
{
  __shared__ __align__(16) char lds[8192 + 8192 + 2 * 2048];
  char* lds_k = lds;
  char* lds_v = lds + 8192;

  const int tid = threadIdx.x;
  const int qi = (T_ / BQ - 1) - blockIdx.x;   // reversed: longest first
  const int b  = blockIdx.y;
  const int qblk = qi * BQ;
  const int wave = tid >> 6;
  const int lane = tid & 63;
  const int lrow = lane & 15;
  const int lgrp = lane >> 4;
  const int swzA = (lrow & 7) << 4;
  char* lds_p = lds + 16384 + wave * 2048;

  const short* Q = (const short*)qb + (size_t)b * T_ * H_;
  const short* K = (const short*)kb + (size_t)b * T_ * H_;
  const short* V = (const short*)vb + (size_t)b * T_ * H_;

  const int qrow0 = qblk + wave * 16;   // this wave's first q row
  const bf16x8 qf0 = *(const bf16x8*)(Q + (size_t)(qrow0 + lrow) * H_ + lgrp * 8);
  const bf16x8 qf1 = *(const bf16x8*)(Q + (size_t)(qrow0 + lrow) * H_ + 32 + lgrp * 8);

  f32x4 o[4];
  float m[4], l[4];
  #pragma unroll
  for (int n = 0; n < 4; ++n) o[n] = f32x4{0.f, 0.f, 0.f, 0.f};
  #pragma unroll
  for (int r = 0; r < 4; ++r) { m[r] = -INFINITY; l[r] = 0.f; }

  const float sc = 0.05103103630798288f;   // 384^-0.5

  const int nch = (qblk + BQ + KVB - 1) / KVB;

  // staging decomposition: t = a*4+c; rows {2a,2a+1}, col16 {c,c+4}
  const int sa = tid >> 2;
  const int scp = tid & 3;

  bf16x8 kreg[2][2], vreg[2][2];
  // prologue: load chunk 0
  #pragma unroll
  for (int i = 0; i < 2; ++i)
    #pragma unroll
    for (int ci = 0; ci < 2; ++ci) {
      const size_t go = (size_t)(2 * sa + i) * H_ + (scp + 4 * ci) * 8;
      kreg[i][ci] = *(const bf16x8*)(K + go);
      vreg[i][ci] = *(const bf16x8*)(V + go);
    }

  for (int ch = 0; ch < nch; ++ch) {
    const int kv0 = ch * KVB;
    __syncthreads();   // prev chunk's LDS reads complete

    // regs -> LDS (K direct, V transposed as packed pairs)
    #pragma unroll
    for (int i = 0; i < 2; ++i)
      #pragma unroll
      for (int ci = 0; ci < 2; ++ci) {
        const int r = 2 * sa + i, cc = scp + 4 * ci;
        *(bf16x8*)(lds_k + ((r * 128 + cc * 16) ^ ((r & 7) << 4))) = kreg[i][ci];
      }
    #pragma unroll
    for (int ci = 0; ci < 2; ++ci)
      #pragma unroll
      for (int j = 0; j < 8; ++j) {
        const unsigned lo = (unsigned short)vreg[0][ci][j];
        const unsigned hi = (unsigned short)vreg[1][ci][j];
        const int h = (scp + 4 * ci) * 8 + j;
        *(unsigned*)(lds_v + ((h * 128 + sa * 4) ^ ((h & 7) << 4))) = lo | (hi << 16);
      }
    __syncthreads();   // staging visible

    // prefetch next chunk into regs (in flight during compute)
    if (ch + 1 < nch) {
      const size_t nb = (size_t)(kv0 + KVB) * H_;
      #pragma unroll
      for (int i = 0; i < 2; ++i)
        #pragma unroll
        for (int ci = 0; ci < 2; ++ci) {
          const size_t go = nb + (size_t)(2 * sa + i) * H_ + (scp + 4 * ci) * 8;
          kreg[i][ci] = *(const bf16x8*)(K + go);
          vreg[i][ci] = *(const bf16x8*)(V + go);
        }
    }

    // ---- S = Q K^T : 4 tiles of 16 kv ----
    f32x4 s[4];
    #pragma unroll
    for (int t4 = 0; t4 < 4; ++t4) {
      s[t4] = f32x4{0.f, 0.f, 0.f, 0.f};
      const int rb2 = (t4 * 16 + lrow) * 128;
      const bf16x8 k0 = *(const bf16x8*)(lds_k + ((rb2 + lgrp * 16) ^ swzA));
      const bf16x8 k1 = *(const bf16x8*)(lds_k + ((rb2 + 64 + lgrp * 16) ^ swzA));
      s[t4] = __builtin_amdgcn_mfma_f32_16x16x32_bf16(qf0, k0, s[t4], 0, 0, 0);
      s[t4] = __builtin_amdgcn_mfma_f32_16x16x32_bf16(qf1, k1, s[t4], 0, 0, 0);
    }

    // ---- scale + causal mask ----
    #pragma unroll
    for (int t4 = 0; t4 < 4; ++t4)
      #pragma unroll
      for (int r = 0; r < 4; ++r) {
        const int rg = qrow0 + lgrp * 4 + r;
        const int col = kv0 + t4 * 16 + lrow;
        s[t4][r] = (col > rg) ? -INFINITY : s[t4][r] * sc;
      }

    // ---- online softmax ----
    float cm[4], cs[4];
    #pragma unroll
    for (int r = 0; r < 4; ++r)
      cm[r] = fmaxf(fmaxf(s[0][r], s[1][r]), fmaxf(s[2][r], s[3][r]));
    #pragma unroll
    for (int d = 1; d < 16; d <<= 1)
      #pragma unroll
      for (int r = 0; r < 4; ++r) cm[r] = fmaxf(cm[r], __shfl_xor(cm[r], d, 64));
    #pragma unroll
    for (int r = 0; r < 4; ++r) {
      const float nm = fmaxf(m[r], cm[r]);
      const float alpha = __expf(m[r] - nm);
      m[r] = nm;
      #pragma unroll
      for (int t4 = 0; t4 < 4; ++t4) s[t4][r] = __expf(s[t4][r] - nm);
      cs[r] = (s[0][r] + s[1][r]) + (s[2][r] + s[3][r]);
      l[r] = l[r] * alpha + cs[r];
      #pragma unroll
      for (int n = 0; n < 4; ++n) o[n][r] *= alpha;
    }
    #pragma unroll
    for (int d = 1; d < 16; d <<= 1)
      #pragma unroll
      for (int r = 0; r < 4; ++r) {
        const float other = __shfl_xor(l[r], d, 64);
        (void)other;
      }
    // NOTE: l row-sum reduction done below properly
    #pragma unroll
    for (int r = 0; r < 4; ++r) l[r] -= cs[r];          // undo, reduce cs first
    #pragma unroll
    for (int d = 1; d < 16; d <<= 1)
      #pragma unroll
      for (int r = 0; r < 4; ++r) cs[r] += __shfl_xor(cs[r], d, 64);
    #pragma unroll
    for (int r = 0; r < 4; ++r) l[r] += cs[r];

    // ---- P (C-layout) -> per-wave LDS (swizzled) -> A-frags ----
    #pragma unroll
    for (int t4 = 0; t4 < 4; ++t4)
      #pragma unroll
      for (int r = 0; r < 4; ++r) {
        const int row = lgrp * 4 + r;
        *(short*)(lds_p + ((row * 128 + (t4 * 16 + lrow) * 2) ^ ((row & 7) << 4))) =
            f2bf(s[t4][r]);
      }
    // same-wave LDS write->read: compiler inserts lgkmcnt
    const bf16x8 pf0 = *(const bf16x8*)(lds_p + ((lrow * 128 + lgrp * 16) ^ swzA));
    const bf16x8 pf1 = *(const bf16x8*)(lds_p + ((lrow * 128 + 64 + lgrp * 16) ^ swzA));

    // ---- O += P V ----
    #pragma unroll
    for (int n = 0; n < 4; ++n) {
      const int rb2 = (n * 16 + lrow) * 128;
      const bf16x8 v0 = *(const bf16x8*)(lds_v + ((rb2 + lgrp * 16) ^ swzA));
      const bf16x8 v1 = *(const bf16x8*)(lds_v + ((rb2 + 64 + lgrp * 16) ^ swzA));
      o[n] = __builtin_amdgcn_mfma_f32_16x16x32_bf16(pf0, v0, o[n], 0, 0, 0);
      o[n] = __builtin_amdgcn_mfma_f32_16x16x32_bf16(pf1, v1, o[n], 0, 0, 0);
    }
  }

  // ---- epilogue ----
  float* op = out + ((size_t)b * T_ + qrow0) * H_;
  #pragma unroll
  for (int r = 0; r < 4; ++r) {
    const float inv = 1.0f / l[r];
    const int row = lgrp * 4 + r;
    #pragma unroll
    for (int n = 0; n < 4; ++n)
      op[row * H_ + n * 16 + lrow] = o[n][r] * inv;
  }
}

extern "C" void kernel_launch(void* const* d_in, const int* in_sizes, int n_in,
                              void* d_out, int out_size, void* d_ws, size_t ws_size,
                              hipStream_t stream) {
  const float* x  = (const float*)d_in[0];
  const float* Wk = (const float*)d_in[1];
  const float* Wq = (const float*)d_in[2];
  const float* Wv = (const float*)d_in[3];
  float* out = (float*)d_out;

  const size_t ntok = (size_t)B_ * T_;          // 16384
  __hip_bfloat16* qb = (__hip_bfloat16*)d_ws;
  __hip_bfloat16* kb = qb + ntok * H_;
  __hip_bfloat16* vb = kb + ntok * H_;
  short* Wt = (short*)(vb + ntok * H_);         // 3 * 64 * 384 bf16

  wconv_kernel<<<3, 256, 0, stream>>>(Wk, Wq, Wv, Wt);
  proj_mfma<<<(int)(ntok / 64), 256, 0, stream>>>(x, Wt, qb, kb, vb);
  attn_kernel<<<dim3(T_ / BQ, B_), 128, 0, stream>>>(qb, kb, vb, out);
}

// Round 3
// 196.039 us; speedup vs baseline: 1.9189x; 1.1930x over previous
//
#include <hip/hip_runtime.h>
#include <hip/hip_bf16.h>
#include <math.h>

#define B_ 4
#define T_ 4096
#define C_ 384
#define H_ 64

typedef __attribute__((ext_vector_type(8))) short bf16x8;
typedef __attribute__((ext_vector_type(4))) float f32x4;

static __device__ __forceinline__ short f2bf(float f) {
  return (short)(((__hip_bfloat16_raw)__float2bfloat16(f)).x);
}

// ---------------- W convert+transpose: Wt[w3][h][c] bf16, w3 in {k,q,v} ------
__global__ __launch_bounds__(256) void wconv_kernel(
    const float* __restrict__ Wk, const float* __restrict__ Wq,
    const float* __restrict__ Wv, short* __restrict__ Wt)
{
  const int w3 = blockIdx.x;
  const float* W = (w3 == 0) ? Wk : (w3 == 1) ? Wq : Wv;
  short* o = Wt + w3 * (H_ * C_);
  for (int i = threadIdx.x; i < H_ * C_; i += 256) {
    const int h = i / C_, c = i - h * C_;
    o[i] = f2bf(W[c * H_ + h]);
  }
}

// ---------------- Projection: no LDS, 12 independent MFMA chains -------------
// Block 256 thr / 4 waves; wave handles 16 rows. k->kb, q->qb, v->vbT[B][H][T].
__global__ __launch_bounds__(256) void proj_mfma(
    const float* __restrict__ x, const short* __restrict__ Wt,
    short* __restrict__ qb, short* __restrict__ kb, short* __restrict__ vbT)
{
  const int tid = threadIdx.x;
  const int wave = tid >> 6, lane = tid & 63;
  const int lrow = lane & 15, lgrp = lane >> 4;
  const int row0 = blockIdx.x * 64 + wave * 16;

  // A-fragments straight from fp32 x, converted in-reg
  bf16x8 af[12];
  #pragma unroll
  for (int ks = 0; ks < 12; ++ks) {
    const float* gp = x + (size_t)(row0 + lrow) * C_ + ks * 32 + lgrp * 8;
    const float4 f0 = *(const float4*)gp;
    const float4 f1 = *(const float4*)(gp + 4);
    bf16x8 bv;
    bv[0] = f2bf(f0.x); bv[1] = f2bf(f0.y); bv[2] = f2bf(f0.z); bv[3] = f2bf(f0.w);
    bv[4] = f2bf(f1.x); bv[5] = f2bf(f1.y); bv[6] = f2bf(f1.z); bv[7] = f2bf(f1.w);
    af[ks] = bv;
  }

  f32x4 acc[3][4];
  #pragma unroll
  for (int w3 = 0; w3 < 3; ++w3)
    #pragma unroll
    for (int n = 0; n < 4; ++n) acc[w3][n] = f32x4{0.f, 0.f, 0.f, 0.f};

  #pragma unroll
  for (int ks = 0; ks < 12; ++ks) {
    #pragma unroll
    for (int w3 = 0; w3 < 3; ++w3)
      #pragma unroll
      for (int n = 0; n < 4; ++n) {
        const bf16x8 bf = *(const bf16x8*)(
            Wt + w3 * (H_ * C_) + (n * 16 + lrow) * C_ + ks * 32 + lgrp * 8);
        acc[w3][n] = __builtin_amdgcn_mfma_f32_16x16x32_bf16(af[ks], bf, acc[w3][n], 0, 0, 0);
      }
  }

  #pragma unroll
  for (int n = 0; n < 4; ++n)
    #pragma unroll
    for (int r = 0; r < 4; ++r) {
      const int row = row0 + lgrp * 4 + r;
      const int h = n * 16 + lrow;
      kb[(size_t)row * H_ + h] = f2bf(acc[0][n][r]);
      qb[(size_t)row * H_ + h] = f2bf(acc[1][n][r]);
      const int bb = row >> 12, tt = row & (T_ - 1);
      vbT[((size_t)bb * H_ + h) * T_ + tt] = f2bf(acc[2][n][r]);   // V pre-transposed
    }
}

// ---------------- Flash attention: 8 waves = 4 KV-splits x 2 q-subtiles ------
#define KVB 64
#define BQ 32
#define NSPL 4

__global__ __launch_bounds__(512, 4) void attn_kernel(
    const short* __restrict__ qb, const short* __restrict__ kb,
    const short* __restrict__ vbT, float* __restrict__ out)
{
  __shared__ __align__(16) char lds[NSPL * 16384 + 8 * 2048];   // 80 KB
  const int tid = threadIdx.x;
  const int wave = tid >> 6, lane = tid & 63;
  const int wq = wave & 1, ws = wave >> 1;
  const int lrow = lane & 15, lgrp = lane >> 4;
  const int swzA = (lrow & 7) << 4;

  const int qi = (T_ / BQ - 1) - blockIdx.x;    // longest blocks first
  const int b  = blockIdx.y;
  const int qblk = qi * BQ;
  const int qrow0 = qblk + wq * 16;

  char* lds_k = lds + ws * 16384;
  char* lds_v = lds_k + 8192;
  char* lds_p = lds + NSPL * 16384 + wave * 2048;

  const short* Q  = qb  + (size_t)b * T_ * H_;
  const short* K  = kb  + (size_t)b * T_ * H_;
  const short* Vt = vbT + (size_t)b * H_ * T_;

  const bf16x8 qf0 = *(const bf16x8*)(Q + (size_t)(qrow0 + lrow) * H_ + lgrp * 8);
  const bf16x8 qf1 = *(const bf16x8*)(Q + (size_t)(qrow0 + lrow) * H_ + 32 + lgrp * 8);

  f32x4 o[4];
  float m[4], l[4];
  #pragma unroll
  for (int n = 0; n < 4; ++n) o[n] = f32x4{0.f, 0.f, 0.f, 0.f};
  #pragma unroll
  for (int r = 0; r < 4; ++r) { m[r] = -INFINITY; l[r] = 0.f; }

  const float sc = 0.05103103630798288f;        // 384^-0.5
  const int nch = (qblk + BQ + KVB - 1) / KVB;  // chunks this q-block needs
  const int nt  = (nch + NSPL - 1) / NSPL;      // lockstep iterations

  const int t2 = wq * 64 + lane;                // 0..127 within split
  const int sa = t2 >> 2, scp = t2 & 3;

  bf16x8 kreg[2][2], vreg[2][2];
  if (ws < nch) {
    const int kv0 = ws * KVB;
    #pragma unroll
    for (int i = 0; i < 2; ++i)
      #pragma unroll
      for (int ci = 0; ci < 2; ++ci) {
        kreg[i][ci] = *(const bf16x8*)(K  + (size_t)(kv0 + 2 * sa + i) * H_ + (scp + 4 * ci) * 8);
        vreg[i][ci] = *(const bf16x8*)(Vt + (size_t)(2 * sa + i) * T_ + kv0 + (scp + 4 * ci) * 8);
      }
  }

  for (int t = 0; t < nt; ++t) {
    const int c4 = t * NSPL + ws;
    const bool act = (c4 < nch);
    const int kv0 = c4 * KVB;

    __syncthreads();            // prev iteration's LDS reads complete
    if (act) {
      #pragma unroll
      for (int i = 0; i < 2; ++i)
        #pragma unroll
        for (int ci = 0; ci < 2; ++ci) {
          const int r = 2 * sa + i, cc = scp + 4 * ci;
          const int off = (r * 128 + cc * 16) ^ ((r & 7) << 4);
          *(bf16x8*)(lds_k + off) = kreg[i][ci];
          *(bf16x8*)(lds_v + off) = vreg[i][ci];
        }
    }
    __syncthreads();            // staging visible

    // prefetch this split's next chunk (in flight during compute)
    const int c4n = c4 + NSPL;
    if (c4n < nch) {
      const int kvn = c4n * KVB;
      #pragma unroll
      for (int i = 0; i < 2; ++i)
        #pragma unroll
        for (int ci = 0; ci < 2; ++ci) {
          kreg[i][ci] = *(const bf16x8*)(K  + (size_t)(kvn + 2 * sa + i) * H_ + (scp + 4 * ci) * 8);
          vreg[i][ci] = *(const bf16x8*)(Vt + (size_t)(2 * sa + i) * T_ + kvn + (scp + 4 * ci) * 8);
        }
    }

    if (act) {
      // ---- S = Q K^T ----
      f32x4 s[4];
      #pragma unroll
      for (int t4 = 0; t4 < 4; ++t4) {
        s[t4] = f32x4{0.f, 0.f, 0.f, 0.f};
        const int rb2 = (t4 * 16 + lrow) * 128;
        const bf16x8 k0 = *(const bf16x8*)(lds_k + ((rb2 + lgrp * 16) ^ swzA));
        const bf16x8 k1 = *(const bf16x8*)(lds_k + ((rb2 + 64 + lgrp * 16) ^ swzA));
        s[t4] = __builtin_amdgcn_mfma_f32_16x16x32_bf16(qf0, k0, s[t4], 0, 0, 0);
        s[t4] = __builtin_amdgcn_mfma_f32_16x16x32_bf16(qf1, k1, s[t4], 0, 0, 0);
      }

      // ---- scale + causal mask ----
      #pragma unroll
      for (int t4 = 0; t4 < 4; ++t4)
        #pragma unroll
        for (int r = 0; r < 4; ++r) {
          const int rg = qrow0 + lgrp * 4 + r;
          const int col = kv0 + t4 * 16 + lrow;
          s[t4][r] = (col > rg) ? -INFINITY : s[t4][r] * sc;
        }

      // ---- online softmax ----
      float cm[4], cs[4];
      #pragma unroll
      for (int r = 0; r < 4; ++r)
        cm[r] = fmaxf(fmaxf(s[0][r], s[1][r]), fmaxf(s[2][r], s[3][r]));
      #pragma unroll
      for (int d = 1; d < 16; d <<= 1)
        #pragma unroll
        for (int r = 0; r < 4; ++r) cm[r] = fmaxf(cm[r], __shfl_xor(cm[r], d, 64));
      #pragma unroll
      for (int r = 0; r < 4; ++r) {
        const float nm = fmaxf(m[r], cm[r]);
        const float alpha = __expf(m[r] - nm);
        m[r] = nm;
        #pragma unroll
        for (int t4 = 0; t4 < 4; ++t4) s[t4][r] = __expf(s[t4][r] - nm);
        cs[r] = (s[0][r] + s[1][r]) + (s[2][r] + s[3][r]);
        #pragma unroll
        for (int n = 0; n < 4; ++n) o[n][r] *= alpha;
        l[r] *= alpha;
      }
      #pragma unroll
      for (int d = 1; d < 16; d <<= 1)
        #pragma unroll
        for (int r = 0; r < 4; ++r) cs[r] += __shfl_xor(cs[r], d, 64);
      #pragma unroll
      for (int r = 0; r < 4; ++r) l[r] += cs[r];

      // ---- P -> per-wave LDS -> A-frags ----
      #pragma unroll
      for (int t4 = 0; t4 < 4; ++t4)
        #pragma unroll
        for (int r = 0; r < 4; ++r) {
          const int row = lgrp * 4 + r;
          *(short*)(lds_p + ((row * 128 + (t4 * 16 + lrow) * 2) ^ ((row & 7) << 4))) =
              f2bf(s[t4][r]);
        }
      const bf16x8 pf0 = *(const bf16x8*)(lds_p + ((lrow * 128 + lgrp * 16) ^ swzA));
      const bf16x8 pf1 = *(const bf16x8*)(lds_p + ((lrow * 128 + 64 + lgrp * 16) ^ swzA));

      // ---- O += P V  (lds_v rows are h, cols kv: conflict-free like K) ----
      #pragma unroll
      for (int n = 0; n < 4; ++n) {
        const int rb2 = (n * 16 + lrow) * 128;
        const bf16x8 v0 = *(const bf16x8*)(lds_v + ((rb2 + lgrp * 16) ^ swzA));
        const bf16x8 v1 = *(const bf16x8*)(lds_v + ((rb2 + 64 + lgrp * 16) ^ swzA));
        o[n] = __builtin_amdgcn_mfma_f32_16x16x32_bf16(pf0, v0, o[n], 0, 0, 0);
        o[n] = __builtin_amdgcn_mfma_f32_16x16x32_bf16(pf1, v1, o[n], 0, 0, 0);
      }
    }
  }

  // ---- combine the 4 KV-split partials via LDS ----
  __syncthreads();
  float* comb = (float*)lds;                       // 8*16*64 f32 = 32 KB
  float* mbuf = (float*)(lds + 32768);             // 128 f32
  float* lbuf = (float*)(lds + 32768 + 512);       // 128 f32
  #pragma unroll
  for (int n = 0; n < 4; ++n)
    #pragma unroll
    for (int r = 0; r < 4; ++r)
      comb[((ws * 2 + wq) * 16 + lgrp * 4 + r) * 64 + n * 16 + lrow] = o[n][r];
  if (lrow == 0) {
    #pragma unroll
    for (int r = 0; r < 4; ++r) {
      mbuf[ws * 32 + wq * 16 + lgrp * 4 + r] = m[r];
      lbuf[ws * 32 + wq * 16 + lgrp * 4 + r] = l[r];
    }
  }
  __syncthreads();

  // wave (ws,wq) merges rows of its wq, column block n = ws
  float* op = out + ((size_t)b * T_ + qblk + wq * 16) * H_;
  #pragma unroll
  for (int r = 0; r < 4; ++r) {
    const int row = lgrp * 4 + r;
    float ms[4], M = -INFINITY;
    #pragma unroll
    for (int s5 = 0; s5 < 4; ++s5) {
      ms[s5] = mbuf[s5 * 32 + wq * 16 + row];
      M = fmaxf(M, ms[s5]);
    }
    float os = 0.f, lsum = 0.f;
    #pragma unroll
    for (int s5 = 0; s5 < 4; ++s5) {
      const float w = __expf(ms[s5] - M);
      os   += w * comb[((s5 * 2 + wq) * 16 + row) * 64 + ws * 16 + lrow];
      lsum += w * lbuf[s5 * 32 + wq * 16 + row];
    }
    op[row * H_ + ws * 16 + lrow] = os / lsum;
  }
}

extern "C" void kernel_launch(void* const* d_in, const int* in_sizes, int n_in,
                              void* d_out, int out_size, void* d_ws, size_t ws_size,
                              hipStream_t stream) {
  const float* x  = (const float*)d_in[0];
  const float* Wk = (const float*)d_in[1];
  const float* Wq = (const float*)d_in[2];
  const float* Wv = (const float*)d_in[3];
  float* out = (float*)d_out;

  const size_t ntok = (size_t)B_ * T_;            // 16384
  short* qb  = (short*)d_ws;
  short* kb  = qb + ntok * H_;
  short* vbT = kb + ntok * H_;
  short* Wt  = vbT + ntok * H_;                   // 3 * 64 * 384 bf16

  wconv_kernel<<<3, 256, 0, stream>>>(Wk, Wq, Wv, Wt);
  proj_mfma<<<(int)(ntok / 64), 256, 0, stream>>>(x, Wt, qb, kb, vbT);
  attn_kernel<<<dim3(T_ / BQ, B_), 512, 0, stream>>>(qb, kb, vbT, out);
}

// Round 8
// 191.641 us; speedup vs baseline: 1.9629x; 1.0230x over previous
//
#include <hip/hip_runtime.h>
#include <hip/hip_bf16.h>
#include <math.h>

#define B_ 4
#define T_ 4096
#define C_ 384
#define H_ 64
#define BQ 32
#define KVB 64
#define NSPL 4

typedef __attribute__((ext_vector_type(8))) short bf16x8;
typedef __attribute__((ext_vector_type(4))) float f32x4;

static __device__ __forceinline__ short f2bf(float f) {
  return (short)(((__hip_bfloat16_raw)__float2bfloat16(f)).x);
}

// ---------------- W convert+transpose: Wt[w3][h][c] bf16 ---------------------
__global__ __launch_bounds__(256) void wconv_kernel(
    const float* __restrict__ Wk, const float* __restrict__ Wq,
    const float* __restrict__ Wv, short* __restrict__ Wt)
{
  const int w3 = blockIdx.y;
  const float* W = (w3 == 0) ? Wk : (w3 == 1) ? Wq : Wv;
  const int i = blockIdx.x * 256 + threadIdx.x;   // i = h*C_ + c
  const int h = i / C_;
  const int c = i - h * C_;
  Wt[w3 * (H_ * C_) + i] = f2bf(W[c * H_ + h]);
}

// ---------------- Projection: grid (256,3), wave = 16 rows x 64 cols ---------
// w3==2 uses swapped operands to emit V^T directly (coalesced stores).
__global__ __launch_bounds__(256, 3) void proj_mfma(
    const float* __restrict__ x, const short* __restrict__ Wt,
    short* __restrict__ qb, short* __restrict__ kb, short* __restrict__ vbT)
{
  const int tid = threadIdx.x;
  const int wave = tid >> 6, lane = tid & 63;
  const int lrow = lane & 15, lgrp = lane >> 4;
  const int row0 = blockIdx.x * 64 + wave * 16;
  const int w3 = blockIdx.y;

  // x A-fragments (also valid as B-fragments: identical lane->element map)
  bf16x8 af[12];
  #pragma unroll
  for (int ks = 0; ks < 12; ++ks) {
    const float* gp = x + (size_t)(row0 + lrow) * C_ + ks * 32 + lgrp * 8;
    const float4 f0 = *(const float4*)gp;
    const float4 f1 = *(const float4*)(gp + 4);
    bf16x8 bv;
    bv[0] = f2bf(f0.x); bv[1] = f2bf(f0.y); bv[2] = f2bf(f0.z); bv[3] = f2bf(f0.w);
    bv[4] = f2bf(f1.x); bv[5] = f2bf(f1.y); bv[6] = f2bf(f1.z); bv[7] = f2bf(f1.w);
    af[ks] = bv;
  }

  const short* Wp = Wt + w3 * (H_ * C_);

  if (w3 == 2) {
    // V^T: acc = Wv^T(16 h-rows) x x^T(16 t-cols); D row=h, col=t
    const int bb = row0 >> 12;
    const int tt = row0 & (T_ - 1);
    #pragma unroll
    for (int n = 0; n < 4; ++n) {
      bf16x8 wf[12];
      #pragma unroll
      for (int ks = 0; ks < 12; ++ks)
        wf[ks] = *(const bf16x8*)(Wp + (n * 16 + lrow) * C_ + ks * 32 + lgrp * 8);
      f32x4 acc = {0.f, 0.f, 0.f, 0.f};
      #pragma unroll
      for (int ks = 0; ks < 12; ++ks)
        acc = __builtin_amdgcn_mfma_f32_16x16x32_bf16(wf[ks], af[ks], acc, 0, 0, 0);
      #pragma unroll
      for (int r = 0; r < 4; ++r)
        vbT[(size_t)(bb * H_ + n * 16 + lgrp * 4 + r) * T_ + tt + lrow] = f2bf(acc[r]);
    }
  } else {
    short* outp = (w3 == 0) ? kb : qb;
    #pragma unroll
    for (int n = 0; n < 4; ++n) {
      bf16x8 wf[12];
      #pragma unroll
      for (int ks = 0; ks < 12; ++ks)
        wf[ks] = *(const bf16x8*)(Wp + (n * 16 + lrow) * C_ + ks * 32 + lgrp * 8);
      f32x4 acc = {0.f, 0.f, 0.f, 0.f};
      #pragma unroll
      for (int ks = 0; ks < 12; ++ks)
        acc = __builtin_amdgcn_mfma_f32_16x16x32_bf16(af[ks], wf[ks], acc, 0, 0, 0);
      #pragma unroll
      for (int r = 0; r < 4; ++r)
        outp[(size_t)(row0 + lgrp * 4 + r) * H_ + n * 16 + lrow] = f2bf(acc[r]);
    }
  }
}

// ---------------- Flash attention: one 2-wave block per (q-tile, KV-split) ---
// Partials (unnormalized o, m, l) -> workspace; merged by merge_kernel.
__global__ __launch_bounds__(128, 4) void attn_kernel(
    const short* __restrict__ qb, const short* __restrict__ kb,
    const short* __restrict__ vbT, float* __restrict__ po,
    float* __restrict__ pm, float* __restrict__ pl)
{
  __shared__ __align__(16) char lds[20480];       // K 8K | V 8K | P 2x2K
  char* lds_k = lds;
  char* lds_v = lds + 8192;

  const int tid = threadIdx.x;
  const int wq = tid >> 6, lane = tid & 63;
  const int lrow = lane & 15, lgrp = lane >> 4;
  const int swzA = (lrow & 7) << 4;
  char* lds_p = lds + 16384 + wq * 2048;

  const int qi = (T_ / BQ - 1) - blockIdx.x;      // longest blocks first
  const int ws = blockIdx.y;                      // KV-split id
  const int b  = blockIdx.z;
  const int qblk = qi * BQ;
  const int qrow0 = qblk + wq * 16;

  const short* Q  = qb  + (size_t)b * T_ * H_;
  const short* K  = kb  + (size_t)b * T_ * H_;
  const short* Vt = vbT + (size_t)b * H_ * T_;

  const bf16x8 qf0 = *(const bf16x8*)(Q + (size_t)(qrow0 + lrow) * H_ + lgrp * 8);
  const bf16x8 qf1 = *(const bf16x8*)(Q + (size_t)(qrow0 + lrow) * H_ + 32 + lgrp * 8);

  f32x4 o[4];
  float m[4], l[4];
  #pragma unroll
  for (int n = 0; n < 4; ++n) o[n] = f32x4{0.f, 0.f, 0.f, 0.f};
  #pragma unroll
  for (int r = 0; r < 4; ++r) { m[r] = -INFINITY; l[r] = 0.f; }

  const float sc = 0.05103103630798288f;          // 384^-0.5
  const int nch = (qblk + BQ + KVB - 1) / KVB;    // causal chunk count

  // staging decomposition over 128 threads: rows {2sa,2sa+1}, 16B col slots
  const int sa = tid >> 2, scp = tid & 3;

  bf16x8 kreg[2][2], vreg[2][2];
  if (ws < nch) {
    const int kv0 = ws * KVB;
    #pragma unroll
    for (int i = 0; i < 2; ++i)
      #pragma unroll
      for (int ci = 0; ci < 2; ++ci) {
        kreg[i][ci] = *(const bf16x8*)(K  + (size_t)(kv0 + 2 * sa + i) * H_ + (scp + 4 * ci) * 8);
        vreg[i][ci] = *(const bf16x8*)(Vt + (size_t)(2 * sa + i) * T_ + kv0 + (scp + 4 * ci) * 8);
      }
  }

  for (int c4 = ws; c4 < nch; c4 += NSPL) {
    const int kv0 = c4 * KVB;

    __syncthreads();                              // prev iter's LDS reads done
    #pragma unroll
    for (int i = 0; i < 2; ++i)
      #pragma unroll
      for (int ci = 0; ci < 2; ++ci) {
        const int r = 2 * sa + i, cc = scp + 4 * ci;
        const int off = (r * 128 + cc * 16) ^ ((r & 7) << 4);
        *(bf16x8*)(lds_k + off) = kreg[i][ci];
        *(bf16x8*)(lds_v + off) = vreg[i][ci];
      }
    __syncthreads();                              // staging visible

    if (c4 + NSPL < nch) {                        // prefetch next chunk
      const int kvn = (c4 + NSPL) * KVB;
      #pragma unroll
      for (int i = 0; i < 2; ++i)
        #pragma unroll
        for (int ci = 0; ci < 2; ++ci) {
          kreg[i][ci] = *(const bf16x8*)(K  + (size_t)(kvn + 2 * sa + i) * H_ + (scp + 4 * ci) * 8);
          vreg[i][ci] = *(const bf16x8*)(Vt + (size_t)(2 * sa + i) * T_ + kvn + (scp + 4 * ci) * 8);
        }
    }

    // ---- S = Q K^T ----
    f32x4 s[4];
    #pragma unroll
    for (int t4 = 0; t4 < 4; ++t4) {
      s[t4] = f32x4{0.f, 0.f, 0.f, 0.f};
      const int rb2 = (t4 * 16 + lrow) * 128;
      const bf16x8 k0 = *(const bf16x8*)(lds_k + ((rb2 + lgrp * 16) ^ swzA));
      const bf16x8 k1 = *(const bf16x8*)(lds_k + ((rb2 + 64 + lgrp * 16) ^ swzA));
      s[t4] = __builtin_amdgcn_mfma_f32_16x16x32_bf16(qf0, k0, s[t4], 0, 0, 0);
      s[t4] = __builtin_amdgcn_mfma_f32_16x16x32_bf16(qf1, k1, s[t4], 0, 0, 0);
    }

    // ---- scale; mask on any chunk reaching past the wave's first row ----
    // (no-mask shortcut valid only if kv0+KVB-1 <= qrow0, i.e. chunk fully
    //  below the diagonal for ALL of this wave's rows)
    if (kv0 + KVB > qrow0) {
      #pragma unroll
      for (int t4 = 0; t4 < 4; ++t4)
        #pragma unroll
        for (int r = 0; r < 4; ++r) {
          const int rg = qrow0 + lgrp * 4 + r;
          const int col = kv0 + t4 * 16 + lrow;
          s[t4][r] = (col > rg) ? -INFINITY : s[t4][r] * sc;
        }
    } else {
      #pragma unroll
      for (int t4 = 0; t4 < 4; ++t4)
        #pragma unroll
        for (int r = 0; r < 4; ++r) s[t4][r] *= sc;
    }

    // ---- online softmax (row reduce over lrow within 16-lane groups) ----
    float cm[4], cs[4];
    #pragma unroll
    for (int r = 0; r < 4; ++r)
      cm[r] = fmaxf(fmaxf(s[0][r], s[1][r]), fmaxf(s[2][r], s[3][r]));
    #pragma unroll
    for (int d = 1; d < 16; d <<= 1)
      #pragma unroll
      for (int r = 0; r < 4; ++r) cm[r] = fmaxf(cm[r], __shfl_xor(cm[r], d, 64));
    #pragma unroll
    for (int r = 0; r < 4; ++r) {
      const float nm = fmaxf(m[r], cm[r]);
      const float alpha = __expf(m[r] - nm);
      m[r] = nm;
      #pragma unroll
      for (int t4 = 0; t4 < 4; ++t4) s[t4][r] = __expf(s[t4][r] - nm);
      cs[r] = (s[0][r] + s[1][r]) + (s[2][r] + s[3][r]);
      #pragma unroll
      for (int n = 0; n < 4; ++n) o[n][r] *= alpha;
      l[r] *= alpha;
    }
    #pragma unroll
    for (int d = 1; d < 16; d <<= 1)
      #pragma unroll
      for (int r = 0; r < 4; ++r) cs[r] += __shfl_xor(cs[r], d, 64);
    #pragma unroll
    for (int r = 0; r < 4; ++r) l[r] += cs[r];

    // ---- P -> per-wave LDS -> A-frags ----
    #pragma unroll
    for (int t4 = 0; t4 < 4; ++t4)
      #pragma unroll
      for (int r = 0; r < 4; ++r) {
        const int row = lgrp * 4 + r;
        *(short*)(lds_p + ((row * 128 + (t4 * 16 + lrow) * 2) ^ ((row & 7) << 4))) =
            f2bf(s[t4][r]);
      }
    const bf16x8 pf0 = *(const bf16x8*)(lds_p + ((lrow * 128 + lgrp * 16) ^ swzA));
    const bf16x8 pf1 = *(const bf16x8*)(lds_p + ((lrow * 128 + 64 + lgrp * 16) ^ swzA));

    // ---- O += P V ----
    #pragma unroll
    for (int n = 0; n < 4; ++n) {
      const int rb2 = (n * 16 + lrow) * 128;
      const bf16x8 v0 = *(const bf16x8*)(lds_v + ((rb2 + lgrp * 16) ^ swzA));
      const bf16x8 v1 = *(const bf16x8*)(lds_v + ((rb2 + 64 + lgrp * 16) ^ swzA));
      o[n] = __builtin_amdgcn_mfma_f32_16x16x32_bf16(pf0, v0, o[n], 0, 0, 0);
      o[n] = __builtin_amdgcn_mfma_f32_16x16x32_bf16(pf1, v1, o[n], 0, 0, 0);
    }
  }

  // ---- write partials (unnormalized o, m, l) ----
  const size_t rowg = (size_t)b * T_ + qrow0;     // + local row below
  float* pob = po + (size_t)ws * (B_ * T_ * H_);
  #pragma unroll
  for (int n = 0; n < 4; ++n)
    #pragma unroll
    for (int r = 0; r < 4; ++r)
      pob[(rowg + lgrp * 4 + r) * H_ + n * 16 + lrow] = o[n][r];
  if (lrow == 0) {
    #pragma unroll
    for (int r = 0; r < 4; ++r) {
      pm[(size_t)ws * (B_ * T_) + rowg + lgrp * 4 + r] = m[r];
      pl[(size_t)ws * (B_ * T_) + rowg + lgrp * 4 + r] = l[r];
    }
  }
}

// ---------------- Merge the NSPL split partials ------------------------------
__global__ __launch_bounds__(256) void merge_kernel(
    const float* __restrict__ po, const float* __restrict__ pm,
    const float* __restrict__ pl, float* __restrict__ out)
{
  const int idx = blockIdx.x * 256 + threadIdx.x; // 0 .. B*T*H-1
  const int row = idx >> 6;
  float ms[NSPL], M = -INFINITY;
  #pragma unroll
  for (int s = 0; s < NSPL; ++s) {
    ms[s] = pm[(size_t)s * (B_ * T_) + row];
    M = fmaxf(M, ms[s]);
  }
  float num = 0.f, den = 0.f;
  #pragma unroll
  for (int s = 0; s < NSPL; ++s) {
    const float w = __expf(ms[s] - M);            // 0 for idle splits
    num += w * po[(size_t)s * (B_ * T_ * H_) + idx];
    den += w * pl[(size_t)s * (B_ * T_) + row];
  }
  out[idx] = num / den;
}

extern "C" void kernel_launch(void* const* d_in, const int* in_sizes, int n_in,
                              void* d_out, int out_size, void* d_ws, size_t ws_size,
                              hipStream_t stream) {
  const float* x  = (const float*)d_in[0];
  const float* Wk = (const float*)d_in[1];
  const float* Wq = (const float*)d_in[2];
  const float* Wv = (const float*)d_in[3];
  float* out = (float*)d_out;

  const size_t ntok = (size_t)B_ * T_;            // 16384
  char* ws = (char*)d_ws;
  short* qb  = (short*)ws;                                  // 2 MB
  short* kb  = qb + ntok * H_;                              // 2 MB
  short* vbT = kb + ntok * H_;                              // 2 MB
  short* Wt  = vbT + ntok * H_;                             // 144 KB
  float* po  = (float*)(ws + 3 * ntok * H_ * 2 + 3 * H_ * C_ * 2);  // 16 MB
  float* pm  = po + (size_t)NSPL * ntok * H_;               // 256 KB
  float* pl  = pm + (size_t)NSPL * ntok;                    // 256 KB

  wconv_kernel<<<dim3(96, 3), 256, 0, stream>>>(Wk, Wq, Wv, Wt);
  proj_mfma<<<dim3((int)(ntok / 64), 3), 256, 0, stream>>>(x, Wt, qb, kb, vbT);
  attn_kernel<<<dim3(T_ / BQ, NSPL, B_), 128, 0, stream>>>(qb, kb, vbT, po, pm, pl);
  merge_kernel<<<(int)(ntok * H_ / 256), 256, 0, stream>>>(po, pm, pl, out);
}